// Round 5
// baseline (87.102 us; speedup 1.0000x reference)
//
#include <hip/hip_runtime.h>

// FHE BSGS: out[b,s] = sum_{t=0..15} x[b,(s+2^t)&0xFFFF] * diag[t,s], rolled by 32768.
// Roll by S/2 on the 2^16 ring == store to column s ^ 0x8000 (coalesced).
//
// v5: exact XCD partitioning. Dispatch assigns workgroups round-robin to the 8 XCDs
// (XCD = blockIdx % 8, measured). With NB=8 batch rows per thread and batch-group
// y = bid & 7, ALL blocks touching batch rows [8y, 8y+8) land on XCD y:
//   - per-XCD x footprint = 8 rows = 2 MB -> resident in the 4 MB per-XCD L2, so the
//     16x x re-reads (252 MB of requests) are L2-served (~34.5 TB/s), not L3 (~14).
//   - diag is read exactly once per XCD (streams; 32 MB total).
//   - HBM-level traffic ~= compulsory (~66 MB).
// Barrier-free: each thread has ~136 independent loads (MLP hides latency; grid is
// only 512 blocks = 8 waves/CU, but v1 showed this streaming shape saturates the
// fabric). diag float4s amortized 8x from registers.

#define SLOTS 65536
#define MASK  65535
#define NB    8

__global__ __launch_bounds__(256) void bsgs_kernel(
    const float* __restrict__ x,
    const float* __restrict__ diag,
    float* __restrict__ out)
{
    const int bid  = blockIdx.x;          // 0..511
    const int y    = bid & 7;             // batch group == XCD (round-robin bid%8)
    const int xidx = bid >> 3;            // column tile 0..63
    const int j    = xidx * 1024 + threadIdx.x * 4;   // column base (multiple of 4)
    const int bg   = y * NB;              // batches [bg, bg+8) -- all on this XCD

    const float* __restrict__ xb = x + (size_t)bg * SLOTS;

    float4 acc[NB];
#pragma unroll
    for (int b = 0; b < NB; ++b) acc[b] = make_float4(0.f, 0.f, 0.f, 0.f);

    // t = 0,1,2 (shifts 1,2,4) via sliding window: vA = x[j..j+3], vB = x[j+4..j+7]
    {
        const float4 d0 = *(const float4*)(diag + 0 * SLOTS + j);
        const float4 d1 = *(const float4*)(diag + 1 * SLOTS + j);
        const float4 d2 = *(const float4*)(diag + 2 * SLOTS + j);
#pragma unroll
        for (int b = 0; b < NB; ++b) {
            const float* xr = xb + (size_t)b * SLOTS;
            const float4 vA = *(const float4*)(xr + j);
            const float4 vB = *(const float4*)(xr + ((j + 4) & MASK));
            acc[b].x += vA.y * d0.x + vA.z * d1.x + vB.x * d2.x;
            acc[b].y += vA.z * d0.y + vA.w * d1.y + vB.y * d2.y;
            acc[b].z += vA.w * d0.z + vB.x * d1.z + vB.z * d2.z;
            acc[b].w += vB.x * d0.w + vB.y * d1.w + vB.w * d2.w;
        }
    }

    // t = 3..15 (shifts 8..32768): aligned float4 x-loads; diag reused across 8 rows
#pragma unroll
    for (int t = 3; t < 16; ++t) {
        const float4 d = *(const float4*)(diag + t * SLOTS + j);
        const int o = (j + (1 << t)) & MASK;
#pragma unroll
        for (int b = 0; b < NB; ++b) {
            const float4 v = *(const float4*)(xb + (size_t)b * SLOTS + o);
            acc[b].x += v.x * d.x; acc[b].y += v.y * d.y;
            acc[b].z += v.z * d.z; acc[b].w += v.w * d.w;
        }
    }

    // roll by 32768 == XOR top column bit; stores stay coalesced
#pragma unroll
    for (int b = 0; b < NB; ++b)
        *(float4*)(out + (size_t)(bg + b) * SLOTS + (j ^ 32768)) = acc[b];
}

extern "C" void kernel_launch(void* const* d_in, const int* in_sizes, int n_in,
                              void* d_out, int out_size, void* d_ws, size_t ws_size,
                              hipStream_t stream) {
    const float* x    = (const float*)d_in[0];   // (64, 65536) fp32
    const float* diag = (const float*)d_in[1];   // (16, 65536) fp32
    float* out        = (float*)d_out;           // (64, 65536) fp32
    // d_in[2] = stride (1), d_in[3] = reps (1) -- compile-time constants here.

    bsgs_kernel<<<dim3(512), dim3(256), 0, stream>>>(x, diag, out);
}

// Round 6
// 84.302 us; speedup vs baseline: 1.0332x; 1.0332x over previous
//
#include <hip/hip_runtime.h>

// FHE BSGS: out[b,s] = sum_{t=0..15} x[b,(s+2^t)&0xFFFF] * diag[t,s], rolled by 32768.
// Roll by S/2 on the 2^16 ring == store to column s ^ 0x8000 (coalesced).
//
// v6: v4 shape (NB=4, 1024 blocks, barrier-free, diag-in-registers) with x-loads
// cut 15 -> 9 per row via wave-level shuffles on the idle DS pipe:
//   - wave spans 256 cols; vA = x[j], vE = x[j+256]. Window at shift 4k (k=1..32)
//     = shfl(vA, lane+k) if lane+k<64 else shfl(vE, (lane+k)&63)  -> t=2..7 free of loads
//   - shifts 1,2 = component slides of vA / shift-4 window (no ops)
//   - shift 256 = vE itself; only t=9..15 load directly.
// Request bytes 336 -> 237 MB at UNCHANGED block concurrency (calibration across
// v1/v4/v5 shows serving rate scales with #blocks: cut bytes, not blocks).

#define SLOTS 65536
#define MASK  65535
#define NB    4

__device__ __forceinline__ float4 shfl4(const float4 v, int lsel) {
    return make_float4(__shfl(v.x, lsel, 64), __shfl(v.y, lsel, 64),
                       __shfl(v.z, lsel, 64), __shfl(v.w, lsel, 64));
}

__global__ __launch_bounds__(256) void bsgs_kernel(
    const float* __restrict__ x,
    const float* __restrict__ diag,
    float* __restrict__ out)
{
    const int bid  = blockIdx.x;          // 0..1023
    const int y    = bid & 15;            // batch group (XCD-friendly: bid%8 clusters)
    const int xidx = bid >> 4;            // column tile 0..63
    const int j    = xidx * 1024 + threadIdx.x * 4;   // column base (multiple of 4)
    const int bg   = y * NB;
    const int lane = threadIdx.x & 63;

    // diag[t, j..j+3], t=0..15 -- reused across NB batch rows.
    float4 dreg[16];
#pragma unroll
    for (int t = 0; t < 16; ++t)
        dreg[t] = *(const float4*)(diag + t * SLOTS + j);

    float4 acc[NB];
#pragma unroll
    for (int b = 0; b < NB; ++b) acc[b] = make_float4(0.f, 0.f, 0.f, 0.f);

#pragma unroll
    for (int b = 0; b < NB; ++b) {
        const float* __restrict__ xr = x + (size_t)(bg + b) * SLOTS;

        // 9 loads per row: vA, vE, and the 7 big shifts.
        const float4 vA = *(const float4*)(xr + j);
        const float4 vE = *(const float4*)(xr + ((j + 256) & MASK));
        float4 vd[7];
#pragma unroll
        for (int t = 9; t < 16; ++t)
            vd[t - 9] = *(const float4*)(xr + ((j + (1 << t)) & MASK));

        // Windows at shifts 4,8,16,32,64,128 via cross-lane shuffles (DS pipe).
        float4 w[6];
#pragma unroll
        for (int i = 0; i < 6; ++i) {
            const int k  = 1 << i;             // lane offset = shift/4
            const int lp = lane + k;           // source lane (may spill into vE's window)
            const int ls = lp & 63;
            const float4 a = shfl4(vA, ls);
            const float4 e = shfl4(vE, ls);
            const bool useA = lp < 64;
            w[i] = make_float4(useA ? a.x : e.x, useA ? a.y : e.y,
                               useA ? a.z : e.z, useA ? a.w : e.w);
        }

        // t=0 (shift 1): (vA.y, vA.z, vA.w, w0.x);  t=1 (shift 2): (vA.z, vA.w, w0.x, w0.y)
        acc[b].x += vA.y   * dreg[0].x + vA.z   * dreg[1].x;
        acc[b].y += vA.z   * dreg[0].y + vA.w   * dreg[1].y;
        acc[b].z += vA.w   * dreg[0].z + w[0].x * dreg[1].z;
        acc[b].w += w[0].x * dreg[0].w + w[0].y * dreg[1].w;

        // t=2..7 (shifts 4..128): shuffle windows
#pragma unroll
        for (int t = 2; t <= 7; ++t) {
            const float4 v = w[t - 2];
            acc[b].x += v.x * dreg[t].x; acc[b].y += v.y * dreg[t].y;
            acc[b].z += v.z * dreg[t].z; acc[b].w += v.w * dreg[t].w;
        }
        // t=8 (shift 256): vE directly
        acc[b].x += vE.x * dreg[8].x; acc[b].y += vE.y * dreg[8].y;
        acc[b].z += vE.z * dreg[8].z; acc[b].w += vE.w * dreg[8].w;
        // t=9..15 (shifts 512..32768): direct loads
#pragma unroll
        for (int t = 9; t < 16; ++t) {
            const float4 v = vd[t - 9];
            acc[b].x += v.x * dreg[t].x; acc[b].y += v.y * dreg[t].y;
            acc[b].z += v.z * dreg[t].z; acc[b].w += v.w * dreg[t].w;
        }
    }

    // roll by 32768 == XOR top column bit; stores stay coalesced
#pragma unroll
    for (int b = 0; b < NB; ++b)
        *(float4*)(out + (size_t)(bg + b) * SLOTS + (j ^ 32768)) = acc[b];
}

extern "C" void kernel_launch(void* const* d_in, const int* in_sizes, int n_in,
                              void* d_out, int out_size, void* d_ws, size_t ws_size,
                              hipStream_t stream) {
    const float* x    = (const float*)d_in[0];   // (64, 65536) fp32
    const float* diag = (const float*)d_in[1];   // (16, 65536) fp32
    float* out        = (float*)d_out;           // (64, 65536) fp32
    // d_in[2] = stride (1), d_in[3] = reps (1) -- compile-time constants here.

    bsgs_kernel<<<dim3(1024), dim3(256), 0, stream>>>(x, diag, out);
}